// Round 8
// baseline (20762.440 us; speedup 1.0000x reference)
//
#include <hip/hip_runtime.h>

#define T_SEQ 8192
#define HDIM  2048
#define EDIM  2048
#define RBLK  64                      // recurrence blocks
#define ROWS_PER_BLK (HDIM / RBLK)    // 32 rows/block, 4 rows/wave

typedef unsigned long long u64;
typedef __attribute__((ext_vector_type(4))) unsigned int u32x4;
typedef __attribute__((ext_vector_type(4))) float f32x4;

// two 16B agent-coherent loads + full drain (R6 poll)
__device__ inline void poll_pair(const u64* p0, const u64* p1, u32x4& a, u32x4& b) {
    asm volatile("global_load_dwordx4 %0, %2, off sc1\n\t"
                 "global_load_dwordx4 %1, %3, off sc1\n\t"
                 "s_waitcnt vmcnt(0)"
                 : "=v"(a), "=v"(b) : "v"(p0), "v"(p1) : "memory");
}

// Non-rematerializable 16B load: result MUST live in VGPRs (asm output).
__device__ inline f32x4 ld_w16(const float* p) {
    f32x4 r;
    asm volatile("global_load_dwordx4 %0, %1, off" : "=v"(r) : "v"(p));
    return r;
}
// 4B asm load, no compiler waitcnt tracking; drained by a later poll vmcnt(0).
__device__ inline float ld_xp(const float* p) {
    float r;
    asm volatile("global_load_dword %0, %1, off" : "=v"(r) : "v"(p));
    return r;
}

// tanh via e^{2z}: clamp +-15, exp2, rcp. ~6 VALU ops, err ~1e-6.
__device__ inline float fast_tanh(float z) {
    float zc = fminf(fmaxf(z, -15.f), 15.f);
    float zs = zc * 2.88539008177792681f;   // 2*log2(e)
    float ez; asm("v_exp_f32 %0, %1" : "=v"(ez) : "v"(zs));
    float rc; float ezp = ez + 1.f;
    asm("v_rcp_f32 %0, %1" : "=v"(rc) : "v"(ezp));
    return (ez - 1.f) * rc;
}

// ---------------------------------------------------------------------------
// GEMM (NT): C[m][n] = sum_k A[m][k] * B[n][k] + bias[n]
// ---------------------------------------------------------------------------
__global__ __launch_bounds__(256) void gemm_nt_bias(
    const float* __restrict__ A, const float* __restrict__ B,
    const float* __restrict__ bias, float* __restrict__ C,
    int M, int N, int K)
{
    constexpr int BK = 32;
    __shared__ float As[BK][64 + 4];
    __shared__ float Bs[BK][64 + 4];

    const int tx = threadIdx.x & 15;
    const int ty = threadIdx.x >> 4;
    const int m0 = blockIdx.y * 64;
    const int n0 = blockIdx.x * 64;

    float acc[4][4] = {};

    for (int kk = 0; kk < K; kk += BK) {
        #pragma unroll
        for (int p = 0; p < 8; ++p) {
            int idx = p * 256 + threadIdx.x;
            int r = idx >> 5;
            int c = idx & 31;
            As[c][r] = A[(size_t)(m0 + r) * K + kk + c];
            Bs[c][r] = B[(size_t)(n0 + r) * K + kk + c];
        }
        __syncthreads();
        #pragma unroll
        for (int k = 0; k < BK; ++k) {
            float4 a = *(const float4*)&As[k][ty * 4];
            float4 b = *(const float4*)&Bs[k][tx * 4];
            float av[4] = {a.x, a.y, a.z, a.w};
            float bv[4] = {b.x, b.y, b.z, b.w};
            #pragma unroll
            for (int i = 0; i < 4; ++i)
                #pragma unroll
                for (int j = 0; j < 4; ++j)
                    acc[i][j] = fmaf(av[i], bv[j], acc[i][j]);
        }
        __syncthreads();
    }

    float4 bb = *(const float4*)&bias[n0 + tx * 4];
    float bvv[4] = {bb.x, bb.y, bb.z, bb.w};
    #pragma unroll
    for (int i = 0; i < 4; ++i) {
        float4 o;
        o.x = acc[i][0] + bvv[0];
        o.y = acc[i][1] + bvv[1];
        o.z = acc[i][2] + bvv[2];
        o.w = acc[i][3] + bvv[3];
        *(float4*)&C[(size_t)(m0 + ty * 4 + i) * N + n0 + tx * 4] = o;
    }
}

// ---------------------------------------------------------------------------
// Recurrence, 64 blocks x 512 threads. Wave w of block b owns rows
// b*32 + w*4 .. +3. W_h via asm loads -> 128 VGPRs resident.
//
// Sync: hbuf[2][HDIM] of u64 (tag<<32 | f32bits); tag travels with data.
// Simple R6 poll (issue 2x dwordx4 sc1, vmcnt(0), check) — R7's pipelined
// variant regressed. KEY FIX vs R6: vmcnt is FIFO, so any load issued
// before the poll stalls the poll's vmcnt(0). xp is therefore prefetched
// THREE steps ahead via asm loads issued right after poll success: ~1 full
// step of cover, drained for free by a later poll. Per-lane xp address
// r0+(lane&3) matches the post-fold lane->row mapping (no select, 16B/wave).
// Overwrite of the recycled buffer is safe: a wave's tag-t store
// value-depends on ALL its step-(t-1) loads, and poll success requires all
// 2048 tag-t words.
// ---------------------------------------------------------------------------
__global__ __launch_bounds__(512, 1) void rnn_recurrence(
    const float* __restrict__ Wh, const float* __restrict__ xp,
    float* __restrict__ Hs, u64* __restrict__ hbuf, int T)
{
    const int tid  = threadIdx.x;
    const int lane = tid & 63;
    const int wid  = tid >> 6;                              // 0..7
    const int r0   = blockIdx.x * ROWS_PER_BLK + wid * 4;   // wave's first row

    const float* wr0 = Wh + (size_t)(r0 + 0) * HDIM + lane * 4;
    const float* wr1 = Wh + (size_t)(r0 + 1) * HDIM + lane * 4;
    const float* wr2 = Wh + (size_t)(r0 + 2) * HDIM + lane * 4;
    const float* wr3 = Wh + (size_t)(r0 + 3) * HDIM + lane * 4;

    // 32 asm-loaded float4 = 128 VGPRs of W_h, register-resident (non-remat)
    f32x4 w00 = ld_w16(wr0 + 0*256), w01 = ld_w16(wr0 + 1*256), w02 = ld_w16(wr0 + 2*256), w03 = ld_w16(wr0 + 3*256);
    f32x4 w04 = ld_w16(wr0 + 4*256), w05 = ld_w16(wr0 + 5*256), w06 = ld_w16(wr0 + 6*256), w07 = ld_w16(wr0 + 7*256);
    f32x4 w10 = ld_w16(wr1 + 0*256), w11 = ld_w16(wr1 + 1*256), w12 = ld_w16(wr1 + 2*256), w13 = ld_w16(wr1 + 3*256);
    f32x4 w14 = ld_w16(wr1 + 4*256), w15 = ld_w16(wr1 + 5*256), w16 = ld_w16(wr1 + 6*256), w17 = ld_w16(wr1 + 7*256);
    f32x4 w20 = ld_w16(wr2 + 0*256), w21 = ld_w16(wr2 + 1*256), w22 = ld_w16(wr2 + 2*256), w23 = ld_w16(wr2 + 3*256);
    f32x4 w24 = ld_w16(wr2 + 4*256), w25 = ld_w16(wr2 + 5*256), w26 = ld_w16(wr2 + 6*256), w27 = ld_w16(wr2 + 7*256);
    f32x4 w30 = ld_w16(wr3 + 0*256), w31 = ld_w16(wr3 + 1*256), w32 = ld_w16(wr3 + 2*256), w33 = ld_w16(wr3 + 3*256);
    f32x4 w34 = ld_w16(wr3 + 4*256), w35 = ld_w16(wr3 + 5*256), w36 = ld_w16(wr3 + 6*256), w37 = ld_w16(wr3 + 7*256);

    __shared__ float hsm[HDIM];

    // per-lane xp pointer: lane l reads row r0+(l&3) (matches post-fold lanes)
    const float* xpr = xp + r0 + (lane & 3);

    // prime the 3-deep xp pipeline (t = 0,1,2)
    float xqA = ld_xp(xpr + 0 * HDIM);
    float xqB = ld_xp(xpr + (size_t)(T > 1 ? 1 : 0) * HDIM);
    float xqC = ld_xp(xpr + (size_t)(T > 2 ? 2 : 0) * HDIM);
    asm volatile("s_waitcnt vmcnt(0)" ::: "memory");

    for (int t = 0; t < T; ++t) {
        float sv = 0.f;   // lane l ends up holding row r0+(l&3)'s sum
        if (t > 0) {
            const u64* hb = hbuf + (size_t)(t & 1) * HDIM;
            const unsigned tg = (unsigned)t;
            const u64* p0 = hb + 2 * tid;          // rows 2*tid, 2*tid+1
            const u64* p1 = hb + 1024 + 2 * tid;   // rows 1024+2*tid, +1

            u32x4 a, b;
            poll_pair(p0, p1, a, b);
            while ((a.y != tg) | (a.w != tg) | (b.y != tg) | (b.w != tg))
                poll_pair(p0, p1, a, b);

            // prefetch xp for t+2 NOW (vmcnt clean; ~1 step of cover before a
            // poll drains it). Asm load -> no compiler-inserted waitcnt.
            {
                int tt = (t + 2 < T) ? t + 2 : T - 1;
                float xqN = ld_xp(xpr + (size_t)tt * HDIM);
                // rotate pipeline
                float xu = xqA; xqA = xqB; xqB = xqC; xqC = xqN;
                sv = xu;      // stash current xq in sv's slot temporarily
            }
            float xq_cur = sv; sv = 0.f;

            ((float2*)hsm)[tid] =
                make_float2(__uint_as_float(a.x), __uint_as_float(a.z));
            ((float2*)hsm)[tid + 512] =
                make_float2(__uint_as_float(b.x), __uint_as_float(b.z));
            asm volatile("s_waitcnt lgkmcnt(0)" ::: "memory");
            __builtin_amdgcn_s_barrier();
            __builtin_amdgcn_sched_barrier(0);

            float s0 = 0.f, s1 = 0.f, s2 = 0.f, s3 = 0.f;
            #define RNN_STEP(IDX, WA, WB, WC, WD)                                   \
            {   float4 h4 = ((const float4*)hsm)[(IDX) * 64 + lane];                \
                s0 = fmaf(WA.x, h4.x, s0); s0 = fmaf(WA.y, h4.y, s0);               \
                s0 = fmaf(WA.z, h4.z, s0); s0 = fmaf(WA.w, h4.w, s0);               \
                s1 = fmaf(WB.x, h4.x, s1); s1 = fmaf(WB.y, h4.y, s1);               \
                s1 = fmaf(WB.z, h4.z, s1); s1 = fmaf(WB.w, h4.w, s1);               \
                s2 = fmaf(WC.x, h4.x, s2); s2 = fmaf(WC.y, h4.y, s2);               \
                s2 = fmaf(WC.z, h4.z, s2); s2 = fmaf(WC.w, h4.w, s2);               \
                s3 = fmaf(WD.x, h4.x, s3); s3 = fmaf(WD.y, h4.y, s3);               \
                s3 = fmaf(WD.z, h4.z, s3); s3 = fmaf(WD.w, h4.w, s3); }
            RNN_STEP(0, w00, w10, w20, w30)
            RNN_STEP(1, w01, w11, w21, w31)
            RNN_STEP(2, w02, w12, w22, w32)
            RNN_STEP(3, w03, w13, w23, w33)
            RNN_STEP(4, w04, w14, w24, w34)
            RNN_STEP(5, w05, w15, w25, w35)
            RNN_STEP(6, w06, w16, w26, w36)
            RNN_STEP(7, w07, w17, w27, w37)
            #undef RNN_STEP

            // 4-chain fold: 8 shfl total, lane l ends with row (l&3)'s sum.
            float fa = (lane & 1) ? s1 : s0;
            float fb = (lane & 1) ? s0 : s1;
            fa += __shfl_xor(fb, 1);
            float fc = (lane & 1) ? s3 : s2;
            float fd = (lane & 1) ? s2 : s3;
            fc += __shfl_xor(fd, 1);
            float fe = (lane & 2) ? fc : fa;
            float ff = (lane & 2) ? fa : fc;
            fe += __shfl_xor(ff, 2);
            #pragma unroll
            for (int off = 4; off < 64; off <<= 1) fe += __shfl_xor(fe, off);
            sv = fe + xq_cur;
        } else {
            sv = xqA;           // t == 0: z = xp[0][row]
            float xu = xqA; xqA = xqB; xqB = xqC; xqC = xu;  // rotate (t=2 dup ok: t>=1 reloads)
        }

        float hn = fast_tanh(sv);
        if (lane < 4) {
            // tagged store FIRST (critical path), Hs store after
            u64 pk = ((u64)(unsigned)(t + 1) << 32) | (u64)__float_as_uint(hn);
            __hip_atomic_store(&hbuf[(size_t)((t + 1) & 1) * HDIM + r0 + lane], pk,
                               __ATOMIC_RELAXED, __HIP_MEMORY_SCOPE_AGENT);
            Hs[(size_t)t * HDIM + r0 + lane] = hn;   // consumed by next dispatch
        }
    }
}

// ---------------------------------------------------------------------------
// Row softmax over EDIM=2048: one block (256 threads) per row.
// ---------------------------------------------------------------------------
__global__ __launch_bounds__(256) void softmax_rows(
    const float* __restrict__ logits, float* __restrict__ out)
{
    const int row = blockIdx.x;
    const float4* in4 = (const float4*)(logits + (size_t)row * EDIM);
    float4* out4 = (float4*)(out + (size_t)row * EDIM);

    float4 v0 = in4[threadIdx.x];
    float4 v1 = in4[threadIdx.x + 256];

    float m = fmaxf(fmaxf(fmaxf(v0.x, v0.y), fmaxf(v0.z, v0.w)),
                    fmaxf(fmaxf(v1.x, v1.y), fmaxf(v1.z, v1.w)));
    #pragma unroll
    for (int off = 32; off > 0; off >>= 1) m = fmaxf(m, __shfl_xor(m, off));

    __shared__ float red[4];
    if ((threadIdx.x & 63) == 0) red[threadIdx.x >> 6] = m;
    __syncthreads();
    m = fmaxf(fmaxf(red[0], red[1]), fmaxf(red[2], red[3]));
    __syncthreads();

    float e[8];
    e[0] = expf(v0.x - m); e[1] = expf(v0.y - m);
    e[2] = expf(v0.z - m); e[3] = expf(v0.w - m);
    e[4] = expf(v1.x - m); e[5] = expf(v1.y - m);
    e[6] = expf(v1.z - m); e[7] = expf(v1.w - m);

    float s = e[0] + e[1] + e[2] + e[3] + e[4] + e[5] + e[6] + e[7];
    #pragma unroll
    for (int off = 32; off > 0; off >>= 1) s += __shfl_xor(s, off);
    if ((threadIdx.x & 63) == 0) red[threadIdx.x >> 6] = s;
    __syncthreads();
    s = red[0] + red[1] + red[2] + red[3];

    float inv = 1.0f / s;
    out4[threadIdx.x]       = make_float4(e[0] * inv, e[1] * inv, e[2] * inv, e[3] * inv);
    out4[threadIdx.x + 256] = make_float4(e[4] * inv, e[5] * inv, e[6] * inv, e[7] * inv);
}

__global__ void copy_vec(const float* __restrict__ src, float* __restrict__ dst, int n)
{
    int i = blockIdx.x * blockDim.x + threadIdx.x;
    if (i < n) dst[i] = src[i];
}

// ---------------------------------------------------------------------------
extern "C" void kernel_launch(void* const* d_in, const int* in_sizes, int n_in,
                              void* d_out, int out_size, void* d_ws, size_t ws_size,
                              hipStream_t stream)
{
    const float* x  = (const float*)d_in[0];   // [T_SEQ][EDIM]
    const float* Wh = (const float*)d_in[1];   // [HDIM][HDIM]
    const float* Wx = (const float*)d_in[2];   // [HDIM][EDIM]
    const float* Wy = (const float*)d_in[3];   // [EDIM][HDIM]
    const float* Bh = (const float*)d_in[4];   // [HDIM]
    const float* By = (const float*)d_in[5];   // [EDIM]

    float* out    = (float*)d_out;
    float* hfinal = out;                 // [HDIM]
    float* hs     = out + HDIM;          // [T_SEQ][HDIM]: holds hs, then probs

    float* xp   = (float*)d_ws;                                   // [T_SEQ][HDIM]
    u64*   hbuf = (u64*)((char*)d_ws + (size_t)T_SEQ * HDIM * 4); // [2][HDIM]
    float* logits = xp;                  // reuse (xp dead after recurrence)

    // clear tagged h buffers so replays never see stale tags
    hipMemsetAsync(hbuf, 0, 2 * HDIM * sizeof(u64), stream);

    // Phase 1: xp = x @ Wx^T + Bh
    gemm_nt_bias<<<dim3(HDIM / 64, T_SEQ / 64), 256, 0, stream>>>(
        x, Wx, Bh, xp, T_SEQ, HDIM, EDIM);

    // Phase 2: recurrence — cooperative launch only to guarantee co-residency
    int T = T_SEQ;
    const float* xp_c = xp;
    void* args[] = {(void*)&Wh, (void*)&xp_c, (void*)&hs, (void*)&hbuf, (void*)&T};
    hipLaunchCooperativeKernel((void*)rnn_recurrence, dim3(RBLK), dim3(512),
                               args, 0, stream);

    // Phase 3: logits = hs @ Wy^T + By
    gemm_nt_bias<<<dim3(EDIM / 64, T_SEQ / 64), 256, 0, stream>>>(
        hs, Wy, By, logits, T_SEQ, EDIM, HDIM);

    // Phase 4: h_final = hs[T-1] (before softmax overwrites hs region)
    copy_vec<<<dim3(HDIM / 256), 256, 0, stream>>>(
        hs + (size_t)(T_SEQ - 1) * HDIM, hfinal, HDIM);

    // Phase 5: softmax rows: logits (ws) -> output region of d_out
    softmax_rows<<<dim3(T_SEQ), 256, 0, stream>>>(logits, hs);
}

// Round 9
// 14823.270 us; speedup vs baseline: 1.4007x; 1.4007x over previous
//
#include <hip/hip_runtime.h>

#define T_SEQ 8192
#define HDIM  2048
#define EDIM  2048
#define RBLK  64                      // recurrence blocks
#define ROWS_PER_BLK (HDIM / RBLK)    // 32 rows/block, 4 rows/wave

typedef unsigned long long u64;
typedef __attribute__((ext_vector_type(4))) unsigned int u32x4;
typedef __attribute__((ext_vector_type(4))) float f32x4;

// two 16B agent-coherent loads + full drain (R6 poll, proven best)
__device__ inline void poll_pair(const u64* p0, const u64* p1, u32x4& a, u32x4& b) {
    asm volatile("global_load_dwordx4 %0, %2, off sc1\n\t"
                 "global_load_dwordx4 %1, %3, off sc1\n\t"
                 "s_waitcnt vmcnt(0)"
                 : "=v"(a), "=v"(b) : "v"(p0), "v"(p1) : "memory");
}

// Non-rematerializable 16B load: result MUST live in VGPRs (asm output).
__device__ inline f32x4 ld_w16(const float* p) {
    f32x4 r;
    asm volatile("global_load_dwordx4 %0, %1, off" : "=v"(r) : "v"(p));
    return r;
}

// tanh via e^{2z}: clamp +-15, exp2, rcp. ~6 VALU ops, err ~1e-6.
// (validated in R8: absmax unchanged at 0.001953)
__device__ inline float fast_tanh(float z) {
    float zc = fminf(fmaxf(z, -15.f), 15.f);
    float zs = zc * 2.88539008177792681f;   // 2*log2(e)
    float ez; asm("v_exp_f32 %0, %1" : "=v"(ez) : "v"(zs));
    float rc; float ezp = ez + 1.f;
    asm("v_rcp_f32 %0, %1" : "=v"(rc) : "v"(ezp));
    return (ez - 1.f) * rc;
}

// ---------------------------------------------------------------------------
// GEMM (NT): C[m][n] = sum_k A[m][k] * B[n][k] + bias[n]
// ---------------------------------------------------------------------------
__global__ __launch_bounds__(256) void gemm_nt_bias(
    const float* __restrict__ A, const float* __restrict__ B,
    const float* __restrict__ bias, float* __restrict__ C,
    int M, int N, int K)
{
    constexpr int BK = 32;
    __shared__ float As[BK][64 + 4];
    __shared__ float Bs[BK][64 + 4];

    const int tx = threadIdx.x & 15;
    const int ty = threadIdx.x >> 4;
    const int m0 = blockIdx.y * 64;
    const int n0 = blockIdx.x * 64;

    float acc[4][4] = {};

    for (int kk = 0; kk < K; kk += BK) {
        #pragma unroll
        for (int p = 0; p < 8; ++p) {
            int idx = p * 256 + threadIdx.x;
            int r = idx >> 5;
            int c = idx & 31;
            As[c][r] = A[(size_t)(m0 + r) * K + kk + c];
            Bs[c][r] = B[(size_t)(n0 + r) * K + kk + c];
        }
        __syncthreads();
        #pragma unroll
        for (int k = 0; k < BK; ++k) {
            float4 a = *(const float4*)&As[k][ty * 4];
            float4 b = *(const float4*)&Bs[k][tx * 4];
            float av[4] = {a.x, a.y, a.z, a.w};
            float bv[4] = {b.x, b.y, b.z, b.w};
            #pragma unroll
            for (int i = 0; i < 4; ++i)
                #pragma unroll
                for (int j = 0; j < 4; ++j)
                    acc[i][j] = fmaf(av[i], bv[j], acc[i][j]);
        }
        __syncthreads();
    }

    float4 bb = *(const float4*)&bias[n0 + tx * 4];
    float bvv[4] = {bb.x, bb.y, bb.z, bb.w};
    #pragma unroll
    for (int i = 0; i < 4; ++i) {
        float4 o;
        o.x = acc[i][0] + bvv[0];
        o.y = acc[i][1] + bvv[1];
        o.z = acc[i][2] + bvv[2];
        o.w = acc[i][3] + bvv[3];
        *(float4*)&C[(size_t)(m0 + ty * 4 + i) * N + n0 + tx * 4] = o;
    }
}

// ---------------------------------------------------------------------------
// Same GEMM, TRANSPOSED output: Ct[n][m] = sum_k A[m][k]*B[n][k] + bias[n].
// Used for xp so the recurrence reads xpT[row][t] with 16-steps-per-line
// locality (consecutive t contiguous) instead of a cold 8KB-strided line
// every step.
// ---------------------------------------------------------------------------
__global__ __launch_bounds__(256) void gemm_nt_bias_tc(
    const float* __restrict__ A, const float* __restrict__ B,
    const float* __restrict__ bias, float* __restrict__ Ct,
    int M, int N, int K)
{
    constexpr int BK = 32;
    __shared__ float As[BK][64 + 4];
    __shared__ float Bs[BK][64 + 4];

    const int tx = threadIdx.x & 15;
    const int ty = threadIdx.x >> 4;
    const int m0 = blockIdx.y * 64;
    const int n0 = blockIdx.x * 64;

    float acc[4][4] = {};

    for (int kk = 0; kk < K; kk += BK) {
        #pragma unroll
        for (int p = 0; p < 8; ++p) {
            int idx = p * 256 + threadIdx.x;
            int r = idx >> 5;
            int c = idx & 31;
            As[c][r] = A[(size_t)(m0 + r) * K + kk + c];
            Bs[c][r] = B[(size_t)(n0 + r) * K + kk + c];
        }
        __syncthreads();
        #pragma unroll
        for (int k = 0; k < BK; ++k) {
            float4 a = *(const float4*)&As[k][ty * 4];
            float4 b = *(const float4*)&Bs[k][tx * 4];
            float av[4] = {a.x, a.y, a.z, a.w};
            float bv[4] = {b.x, b.y, b.z, b.w};
            #pragma unroll
            for (int i = 0; i < 4; ++i)
                #pragma unroll
                for (int j = 0; j < 4; ++j)
                    acc[i][j] = fmaf(av[i], bv[j], acc[i][j]);
        }
        __syncthreads();
    }

    float4 bb = *(const float4*)&bias[n0 + tx * 4];
    float bvv[4] = {bb.x, bb.y, bb.z, bb.w};
    // acc[i][j]: m = m0+ty*4+i, n = n0+tx*4+j. Pack m-consecutive per j.
    #pragma unroll
    for (int j = 0; j < 4; ++j) {
        float4 o;
        o.x = acc[0][j] + bvv[j];
        o.y = acc[1][j] + bvv[j];
        o.z = acc[2][j] + bvv[j];
        o.w = acc[3][j] + bvv[j];
        *(float4*)&Ct[(size_t)(n0 + tx * 4 + j) * M + m0 + ty * 4] = o;
    }
}

// ---------------------------------------------------------------------------
// Recurrence (R6 structure exactly, + fast_tanh + transposed-xp reads).
// 64 blocks x 512 threads; wave w of block b owns rows b*32+w*4..+3; W_h in
// 128 asm-loaded VGPRs/lane. Sync: hbuf[2][HDIM] u64 (tag<<32|f32bits), tag
// travels with data; readers poll 16B sc1 loads; writers relaxed agent-scope
// atomic exchange. Overwrite of the recycled buffer is safe: a wave's tag-t
// store value-depends on ALL its step-(t-1) loads, and poll success requires
// all 2048 tag-t words.
// ---------------------------------------------------------------------------
__global__ __launch_bounds__(512, 1) void rnn_recurrence(
    const float* __restrict__ Wh, const float* __restrict__ xpT,
    float* __restrict__ Hs, u64* __restrict__ hbuf, int T)
{
    const int tid  = threadIdx.x;
    const int lane = tid & 63;
    const int wid  = tid >> 6;                              // 0..7
    const int r0   = blockIdx.x * ROWS_PER_BLK + wid * 4;   // wave's first row

    const float* wr0 = Wh + (size_t)(r0 + 0) * HDIM + lane * 4;
    const float* wr1 = Wh + (size_t)(r0 + 1) * HDIM + lane * 4;
    const float* wr2 = Wh + (size_t)(r0 + 2) * HDIM + lane * 4;
    const float* wr3 = Wh + (size_t)(r0 + 3) * HDIM + lane * 4;

    // 32 asm-loaded float4 = 128 VGPRs of W_h, register-resident (non-remat)
    f32x4 w00 = ld_w16(wr0 + 0*256), w01 = ld_w16(wr0 + 1*256), w02 = ld_w16(wr0 + 2*256), w03 = ld_w16(wr0 + 3*256);
    f32x4 w04 = ld_w16(wr0 + 4*256), w05 = ld_w16(wr0 + 5*256), w06 = ld_w16(wr0 + 6*256), w07 = ld_w16(wr0 + 7*256);
    f32x4 w10 = ld_w16(wr1 + 0*256), w11 = ld_w16(wr1 + 1*256), w12 = ld_w16(wr1 + 2*256), w13 = ld_w16(wr1 + 3*256);
    f32x4 w14 = ld_w16(wr1 + 4*256), w15 = ld_w16(wr1 + 5*256), w16 = ld_w16(wr1 + 6*256), w17 = ld_w16(wr1 + 7*256);
    f32x4 w20 = ld_w16(wr2 + 0*256), w21 = ld_w16(wr2 + 1*256), w22 = ld_w16(wr2 + 2*256), w23 = ld_w16(wr2 + 3*256);
    f32x4 w24 = ld_w16(wr2 + 4*256), w25 = ld_w16(wr2 + 5*256), w26 = ld_w16(wr2 + 6*256), w27 = ld_w16(wr2 + 7*256);
    f32x4 w30 = ld_w16(wr3 + 0*256), w31 = ld_w16(wr3 + 1*256), w32 = ld_w16(wr3 + 2*256), w33 = ld_w16(wr3 + 3*256);
    f32x4 w34 = ld_w16(wr3 + 4*256), w35 = ld_w16(wr3 + 5*256), w36 = ld_w16(wr3 + 6*256), w37 = ld_w16(wr3 + 7*256);
    asm volatile("s_waitcnt vmcnt(0)" ::: "memory");

    __shared__ float hsm[HDIM];

    for (int t = 0; t < T; ++t) {
        // xq load at R6-proven position; with [H][T] layout this line serves
        // 16 consecutive steps -> L1-hot 15/16 of the time.
        float xq = 0.f;
        if (lane < 4) xq = xpT[(size_t)(r0 + lane) * T + t];

        float sv = 0.f;   // lane l ends up holding row r0+(l&3)'s sum
        if (t > 0) {
            const u64* hb = hbuf + (size_t)(t & 1) * HDIM;
            const unsigned tg = (unsigned)t;
            const u64* p0 = hb + 2 * tid;          // rows 2*tid, 2*tid+1
            const u64* p1 = hb + 1024 + 2 * tid;   // rows 1024+2*tid, +1

            u32x4 a, b;
            poll_pair(p0, p1, a, b);
            while ((a.y != tg) | (a.w != tg) | (b.y != tg) | (b.w != tg))
                poll_pair(p0, p1, a, b);

            ((float2*)hsm)[tid] =
                make_float2(__uint_as_float(a.x), __uint_as_float(a.z));
            ((float2*)hsm)[tid + 512] =
                make_float2(__uint_as_float(b.x), __uint_as_float(b.z));
            __syncthreads();

            float s0 = 0.f, s1 = 0.f, s2 = 0.f, s3 = 0.f;
            #define RNN_STEP(IDX, WA, WB, WC, WD)                                   \
            {   float4 h4 = ((const float4*)hsm)[(IDX) * 64 + lane];                \
                s0 = fmaf(WA.x, h4.x, s0); s0 = fmaf(WA.y, h4.y, s0);               \
                s0 = fmaf(WA.z, h4.z, s0); s0 = fmaf(WA.w, h4.w, s0);               \
                s1 = fmaf(WB.x, h4.x, s1); s1 = fmaf(WB.y, h4.y, s1);               \
                s1 = fmaf(WB.z, h4.z, s1); s1 = fmaf(WB.w, h4.w, s1);               \
                s2 = fmaf(WC.x, h4.x, s2); s2 = fmaf(WC.y, h4.y, s2);               \
                s2 = fmaf(WC.z, h4.z, s2); s2 = fmaf(WC.w, h4.w, s2);               \
                s3 = fmaf(WD.x, h4.x, s3); s3 = fmaf(WD.y, h4.y, s3);               \
                s3 = fmaf(WD.z, h4.z, s3); s3 = fmaf(WD.w, h4.w, s3); }
            RNN_STEP(0, w00, w10, w20, w30)
            RNN_STEP(1, w01, w11, w21, w31)
            RNN_STEP(2, w02, w12, w22, w32)
            RNN_STEP(3, w03, w13, w23, w33)
            RNN_STEP(4, w04, w14, w24, w34)
            RNN_STEP(5, w05, w15, w25, w35)
            RNN_STEP(6, w06, w16, w26, w36)
            RNN_STEP(7, w07, w17, w27, w37)
            #undef RNN_STEP

            // 4-chain fold: 8 shfl total, lane l ends with row (l&3)'s sum.
            float fa = (lane & 1) ? s1 : s0;
            float fb = (lane & 1) ? s0 : s1;
            fa += __shfl_xor(fb, 1);
            float fc = (lane & 1) ? s3 : s2;
            float fd = (lane & 1) ? s2 : s3;
            fc += __shfl_xor(fd, 1);
            float fe = (lane & 2) ? fc : fa;
            float ff = (lane & 2) ? fa : fc;
            fe += __shfl_xor(ff, 2);
            #pragma unroll
            for (int off = 4; off < 64; off <<= 1) fe += __shfl_xor(fe, off);
            sv = fe;
            // no trailing barrier: next-step hsm writes are gated by the poll.
        }

        if (lane < 4) {
            float hn = fast_tanh(sv + xq);
            // tagged ATOMIC exchange first (R6 config), Hs store after
            u64 pk = ((u64)(unsigned)(t + 1) << 32) | (u64)__float_as_uint(hn);
            (void)__hip_atomic_exchange(
                &hbuf[(size_t)((t + 1) & 1) * HDIM + r0 + lane], pk,
                __ATOMIC_RELAXED, __HIP_MEMORY_SCOPE_AGENT);
            Hs[(size_t)t * HDIM + r0 + lane] = hn;   // consumed by next dispatch
        }
    }
}

// ---------------------------------------------------------------------------
// Row softmax over EDIM=2048: one block (256 threads) per row.
// ---------------------------------------------------------------------------
__global__ __launch_bounds__(256) void softmax_rows(
    const float* __restrict__ logits, float* __restrict__ out)
{
    const int row = blockIdx.x;
    const float4* in4 = (const float4*)(logits + (size_t)row * EDIM);
    float4* out4 = (float4*)(out + (size_t)row * EDIM);

    float4 v0 = in4[threadIdx.x];
    float4 v1 = in4[threadIdx.x + 256];

    float m = fmaxf(fmaxf(fmaxf(v0.x, v0.y), fmaxf(v0.z, v0.w)),
                    fmaxf(fmaxf(v1.x, v1.y), fmaxf(v1.z, v1.w)));
    #pragma unroll
    for (int off = 32; off > 0; off >>= 1) m = fmaxf(m, __shfl_xor(m, off));

    __shared__ float red[4];
    if ((threadIdx.x & 63) == 0) red[threadIdx.x >> 6] = m;
    __syncthreads();
    m = fmaxf(fmaxf(red[0], red[1]), fmaxf(red[2], red[3]));
    __syncthreads();

    float e[8];
    e[0] = expf(v0.x - m); e[1] = expf(v0.y - m);
    e[2] = expf(v0.z - m); e[3] = expf(v0.w - m);
    e[4] = expf(v1.x - m); e[5] = expf(v1.y - m);
    e[6] = expf(v1.z - m); e[7] = expf(v1.w - m);

    float s = e[0] + e[1] + e[2] + e[3] + e[4] + e[5] + e[6] + e[7];
    #pragma unroll
    for (int off = 32; off > 0; off >>= 1) s += __shfl_xor(s, off);
    if ((threadIdx.x & 63) == 0) red[threadIdx.x >> 6] = s;
    __syncthreads();
    s = red[0] + red[1] + red[2] + red[3];

    float inv = 1.0f / s;
    out4[threadIdx.x]       = make_float4(e[0] * inv, e[1] * inv, e[2] * inv, e[3] * inv);
    out4[threadIdx.x + 256] = make_float4(e[4] * inv, e[5] * inv, e[6] * inv, e[7] * inv);
}

__global__ void copy_vec(const float* __restrict__ src, float* __restrict__ dst, int n)
{
    int i = blockIdx.x * blockDim.x + threadIdx.x;
    if (i < n) dst[i] = src[i];
}

// ---------------------------------------------------------------------------
extern "C" void kernel_launch(void* const* d_in, const int* in_sizes, int n_in,
                              void* d_out, int out_size, void* d_ws, size_t ws_size,
                              hipStream_t stream)
{
    const float* x  = (const float*)d_in[0];   // [T_SEQ][EDIM]
    const float* Wh = (const float*)d_in[1];   // [HDIM][HDIM]
    const float* Wx = (const float*)d_in[2];   // [HDIM][EDIM]
    const float* Wy = (const float*)d_in[3];   // [EDIM][HDIM]
    const float* Bh = (const float*)d_in[4];   // [HDIM]
    const float* By = (const float*)d_in[5];   // [EDIM]

    float* out    = (float*)d_out;
    float* hfinal = out;                 // [HDIM]
    float* hs     = out + HDIM;          // [T_SEQ][HDIM]: holds hs, then probs

    float* xpT  = (float*)d_ws;                                   // [HDIM][T_SEQ]
    u64*   hbuf = (u64*)((char*)d_ws + (size_t)T_SEQ * HDIM * 4); // [2][HDIM]
    float* logits = xpT;                 // reuse (xpT dead after recurrence)

    // clear tagged h buffers so replays never see stale tags
    hipMemsetAsync(hbuf, 0, 2 * HDIM * sizeof(u64), stream);

    // Phase 1: xpT = (x @ Wx^T + Bh)^T   -> [HDIM][T_SEQ]
    gemm_nt_bias_tc<<<dim3(HDIM / 64, T_SEQ / 64), 256, 0, stream>>>(
        x, Wx, Bh, xpT, T_SEQ, HDIM, EDIM);

    // Phase 2: recurrence — cooperative launch only to guarantee co-residency
    int T = T_SEQ;
    const float* xpT_c = xpT;
    void* args[] = {(void*)&Wh, (void*)&xpT_c, (void*)&hs, (void*)&hbuf, (void*)&T};
    hipLaunchCooperativeKernel((void*)rnn_recurrence, dim3(RBLK), dim3(512),
                               args, 0, stream);

    // Phase 3: logits = hs @ Wy^T + By   (normal [T][E] layout)
    gemm_nt_bias<<<dim3(EDIM / 64, T_SEQ / 64), 256, 0, stream>>>(
        hs, Wy, By, logits, T_SEQ, EDIM, HDIM);

    // Phase 4: h_final = hs[T-1] (before softmax overwrites hs region)
    copy_vec<<<dim3(HDIM / 256), 256, 0, stream>>>(
        hs + (size_t)(T_SEQ - 1) * HDIM, hfinal, HDIM);

    // Phase 5: softmax rows: logits (ws) -> output region of d_out
    softmax_rows<<<dim3(T_SEQ), 256, 0, stream>>>(logits, hs);
}